// Round 3
// baseline (663.751 us; speedup 1.0000x reference)
//
#include <hip/hip_runtime.h>
#include <stdint.h>

#define M_DIM 4096
#define K_DIM 4096
#define N_DIM 11008

typedef _Float16 half2v __attribute__((ext_vector_type(2)));
typedef _Float16 half8  __attribute__((ext_vector_type(8)));
typedef float    f32x4  __attribute__((ext_vector_type(4)));

#define SCHED_FENCE() __builtin_amdgcn_sched_barrier(0)

// cvt_pkrtz returns __fp16x2; route through bits (clang _Float16/__fp16 mismatch).
__device__ __forceinline__ unsigned int pkrtz_bits(float a, float b) {
  typedef __fp16 fp16x2 __attribute__((ext_vector_type(2)));
  union { fp16x2 h; unsigned int u; } c;
  c.h = __builtin_amdgcn_cvt_pkrtz(a, b);
  return c.u;
}

// Pack 8 f32 (exactly-fp16-valued) into fp16, Marlin order {0,4,1,5,2,6,3,7}.
__device__ __forceinline__ half8 pack8(float4 lo, float4 hi) {
  union { unsigned int u[4]; half8 v; } r;
  r.u[0] = pkrtz_bits(lo.x, hi.x);
  r.u[1] = pkrtz_bits(lo.y, hi.y);
  r.u[2] = pkrtz_bits(lo.z, hi.z);
  r.u[3] = pkrtz_bits(lo.w, hi.w);
  return r.v;
}

// Pre-pass: X f32 [M][K] -> fp16 [M][K], k-permuted within each octet.
__global__ __launch_bounds__(256) void convert_x(const float* __restrict__ X,
                                                 _Float16* __restrict__ X16) {
  size_t g = (size_t)blockIdx.x * 256 + threadIdx.x;
  const float4* p = (const float4*)(X + g * 8);
  float4 lo = p[0], hi = p[1];
  *(half8*)(X16 + g * 8) = pack8(lo, hi);
}

// 8 nibbles -> 8 fp16 (q - (z+1)), Marlin order; zoff = half2(1025+z,1025+z).
__device__ __forceinline__ half8 unpack8(unsigned int q, half2v zoff) {
  union { unsigned int u; half2v h; } t0, t1, t2, t3;
  t0.u = (q & 0x000F000Fu) | 0x64006400u;
  t1.u = ((q >> 4) & 0x000F000Fu) | 0x64006400u;
  t2.u = ((q >> 8) & 0x000F000Fu) | 0x64006400u;
  t3.u = ((q >> 12) & 0x000F000Fu) | 0x64006400u;
  union { half2v h[4]; half8 v; } r;
  r.h[0] = t0.h - zoff;
  r.h[1] = t1.h - zoff;
  r.h[2] = t2.h - zoff;
  r.h[3] = t3.h - zoff;
  return r.v;
}

// Async global->LDS, 16B/lane. LDS dst = wave-uniform base + lane*16 (m97 pattern).
__device__ __forceinline__ void stage16(const void* g, void* l) {
  __builtin_amdgcn_global_load_lds((__attribute__((address_space(1))) unsigned int*)g,
                                   (__attribute__((address_space(3))) unsigned int*)l,
                                   16, 0, 0);
}

// 128x128 block, BK=64, TRIPLE-buffered LDS (3x16KB), 2-stage-ahead prefetch,
// counted vmcnt (T3+T4). r2 fix: r1's q0/q1/nq register ROTATION forced a
// compiler-inserted vmcnt wait on THIS stage's B loads every stage (the copy
// reads nq), collapsing the B pipeline to depth ~0.5. Now q[3][..] slots are
// indexed by compile-time constants via 3x loop unroll -- no copies, loads
// issued at stage ks are first read at stage ks+2 (~24 VMEM events later), so
// the auto-wait is vmcnt(~20) == free and vmcnt(12) truly keeps 12 in flight.
__global__ __launch_bounds__(256, 3) void gptq_gemm(
    const _Float16* __restrict__ X16,   // fp16 [M][K], Marlin octet order (d_ws)
    const int* __restrict__ QW,         // int32 [K/8][N]
    const int* __restrict__ QZ,         // int32 [1][N/8]
    const float* __restrict__ SC,       // f32 [1][N]
    float* __restrict__ OUT) {          // f32 [M][N]
  const int tid  = threadIdx.x;
  const int lane = tid & 63;
  const int wave = tid >> 6;
  const int wr   = wave >> 1;
  const int wc   = wave & 1;
  const int quad = lane >> 4;
  const int l16  = lane & 15;
  const int bx = blockIdx.x;   // 86
  const int by = blockIdx.y;   // 32

  __shared__ __align__(16) _Float16 ldsA[3 * 1024 * 8];  // 48 KB, 3 buffers

  // Staging: thread t stages chunks c_i = i*256+t (i=0..3); octet=c>>7, m=c&127.
  const _Float16* gA = X16 + (size_t)(by * 128 + (tid & 127)) * K_DIM + (tid >> 7) * 8;
  _Float16* lw = ldsA + (size_t)tid * 8;

  // B: frag row (stage ks, step s) = ks*8 + s*4 + quad; col = bx*128+wc*64+nt*16+l16.
  const int* qp = QW + (size_t)quad * N_DIM + bx * 128 + wc * 64 + l16;

  half2v zoff[4];
  float sc[4];
#pragma unroll
  for (int nt = 0; nt < 4; ++nt) {
    int n = bx * 128 + wc * 64 + nt * 16 + l16;
    int z = (QZ[n >> 3] >> ((n & 7) * 4)) & 15;
    union { unsigned int u; half2v h; } zc;
    unsigned int zb = 0x6400u + (unsigned int)(z + 1);   // fp16 bits of 1025+z
    zc.u = (zb << 16) | zb;
    zoff[nt] = zc.h;
    sc[nt] = SC[n];
  }

  f32x4 acc[4][4] = {};
  int q[3][2][4];   // q[slot][s][nt], slot indices always compile-time constants

  // ---- Prologue: stage 0 -> buf0 + q[0]; stage 1 -> buf1 + q[1].
#pragma unroll
  for (int i = 0; i < 4; ++i)
    stage16(gA + i * 16, lw + i * 2048);
  SCHED_FENCE();
#pragma unroll
  for (int s = 0; s < 2; ++s)
#pragma unroll
    for (int nt = 0; nt < 4; ++nt)
      q[0][s][nt] = qp[(s * 4) * N_DIM + nt * 16];
  SCHED_FENCE();
  gA += 64;
  qp += 8 * N_DIM;
#pragma unroll
  for (int i = 0; i < 4; ++i)
    stage16(gA + i * 16, lw + 8192 + i * 2048);
  SCHED_FENCE();
#pragma unroll
  for (int s = 0; s < 2; ++s)
#pragma unroll
    for (int nt = 0; nt < 4; ++nt)
      q[1][s][nt] = qp[(s * 4) * N_DIM + nt * 16];
  SCHED_FENCE();
  // Drain stage-0's 12 (A0 + q[0] ready); leave stage-1's 12 in flight.
  asm volatile("s_waitcnt vmcnt(12)" ::: "memory");
  __builtin_amdgcn_s_barrier();

  // One stage: RB/WB are compile-time ints. Prefetches stage ks+2 into
  // buf WB / q[WB]; computes stage ks from buf RB / q[RB]; counted barrier.
#define STAGE_BODY(KS, RB, WB)                                                \
  {                                                                           \
    const int ks = (KS);                                                      \
    if (ks < 62) {                                                            \
      gA += 64;                                                               \
      qp += 8 * N_DIM;                                                        \
      _Float16* lb = ldsA + (WB) * 8192 + (size_t)tid * 8;                    \
      _Pragma("unroll")                                                       \
      for (int i = 0; i < 4; ++i)                                             \
        stage16(gA + i * 16, lb + i * 2048);                                  \
      _Pragma("unroll")                                                       \
      for (int s = 0; s < 2; ++s)                                             \
        _Pragma("unroll")                                                     \
        for (int nt = 0; nt < 4; ++nt)                                        \
          q[WB][s][nt] = qp[(s * 4) * N_DIM + nt * 16];                       \
      SCHED_FENCE();                                                          \
    }                                                                         \
    const _Float16* base = ldsA + (RB) * 8192;                                \
    _Pragma("unroll")                                                         \
    for (int s = 0; s < 2; ++s) {                                             \
      half8 a[4];                                                             \
      _Pragma("unroll")                                                       \
      for (int mt = 0; mt < 4; ++mt)                                          \
        a[mt] = *(const half8*)(base +                                        \
                 ((s * 4 + quad) * 128 + wr * 64 + mt * 16 + l16) * 8);       \
      half8 b[4];                                                             \
      _Pragma("unroll")                                                       \
      for (int nt = 0; nt < 4; ++nt)                                          \
        b[nt] = unpack8((unsigned int)q[RB][s][nt], zoff[nt]);                \
      __builtin_amdgcn_s_setprio(1);                                          \
      _Pragma("unroll")                                                       \
      for (int mt = 0; mt < 4; ++mt)                                          \
        _Pragma("unroll")                                                     \
        for (int nt = 0; nt < 4; ++nt)                                        \
          acc[mt][nt] = __builtin_amdgcn_mfma_f32_16x16x32_f16(               \
              a[mt], b[nt], acc[mt][nt], 0, 0, 0);                            \
      __builtin_amdgcn_s_setprio(0);                                          \
    }                                                                         \
    SCHED_FENCE();                                                            \
    if (ks < 62)                                                              \
      asm volatile("s_waitcnt vmcnt(12)" ::: "memory");                       \
    else                                                                      \
      asm volatile("s_waitcnt vmcnt(0)" ::: "memory");                        \
    __builtin_amdgcn_s_barrier();                                             \
  }

  // Stages 0..62 in 21 iterations of 3 (slot = ks % 3 statically).
  for (int it = 0; it < 21; ++it) {
    STAGE_BODY(it * 3 + 0, 0, 2)
    STAGE_BODY(it * 3 + 1, 1, 0)
    STAGE_BODY(it * 3 + 2, 2, 1)
  }
#undef STAGE_BODY

  // ---- Tail stage ks=63: compute only, buf 0 / q[0] (staged at ks=61).
  {
    const _Float16* base = ldsA;
#pragma unroll
    for (int s = 0; s < 2; ++s) {
      half8 a[4];
#pragma unroll
      for (int mt = 0; mt < 4; ++mt)
        a[mt] = *(const half8*)(base + ((s * 4 + quad) * 128 + wr * 64 + mt * 16 + l16) * 8);
      half8 b[4];
#pragma unroll
      for (int nt = 0; nt < 4; ++nt)
        b[nt] = unpack8((unsigned int)q[0][s][nt], zoff[nt]);
      __builtin_amdgcn_s_setprio(1);
#pragma unroll
      for (int mt = 0; mt < 4; ++mt)
#pragma unroll
        for (int nt = 0; nt < 4; ++nt)
          acc[mt][nt] = __builtin_amdgcn_mfma_f32_16x16x32_f16(a[mt], b[nt], acc[mt][nt], 0, 0, 0);
      __builtin_amdgcn_s_setprio(0);
    }
  }

  // Epilogue: C/D layout col=lane&15, row=quad*4+reg (m89-verified).
#pragma unroll
  for (int mt = 0; mt < 4; ++mt) {
    int mbase = by * 128 + wr * 64 + mt * 16 + quad * 4;
#pragma unroll
    for (int nt = 0; nt < 4; ++nt) {
      int n = bx * 128 + wc * 64 + nt * 16 + l16;
      float s = sc[nt];
#pragma unroll
      for (int pp = 0; pp < 4; ++pp)
        OUT[(size_t)(mbase + pp) * N_DIM + n] = acc[mt][nt][pp] * s;
    }
  }
}

extern "C" void kernel_launch(void* const* d_in, const int* in_sizes, int n_in,
                              void* d_out, int out_size, void* d_ws, size_t ws_size,
                              hipStream_t stream) {
  const float* X  = (const float*)d_in[0];
  const int* QW   = (const int*)d_in[1];
  const int* QZ   = (const int*)d_in[2];
  const float* SC = (const float*)d_in[3];
  float* OUT      = (float*)d_out;
  _Float16* X16   = (_Float16*)d_ws;   // 32 MiB; PRE path verified on HW in round 7

  convert_x<<<dim3((M_DIM * (size_t)K_DIM / 8) / 256), 256, 0, stream>>>(X, X16);
  dim3 grid(N_DIM / 128, M_DIM / 128);
  gptq_gemm<<<grid, 256, 0, stream>>>(X16, QW, QZ, SC, OUT);
}